// Round 5
// baseline (324.134 us; speedup 1.0000x reference)
//
#include <hip/hip_runtime.h>

typedef unsigned int uint;
typedef unsigned short ushort;
typedef __attribute__((ext_vector_type(8))) short bf16x8;
typedef __attribute__((ext_vector_type(4))) float floatx4;
typedef __attribute__((ext_vector_type(4))) uint uint4v;
typedef __attribute__((ext_vector_type(2))) uint uint2v;

#define B_   64
#define NR_  16384
#define IC_  16
#define NC_  10
#define OC_  16
#define NCO  160   // NC_*OC_
#define ICO  2560  // IC_*NCO
#define KC_  32    // K chunks (512 r each)
#define KT_  64    // K tile per step

__device__ __forceinline__ float bf2f(ushort h) {
    return __uint_as_float(((uint)h) << 16);
}
__device__ __forceinline__ ushort f2bf(float f) {  // RNE
    uint u = __float_as_uint(f);
    u += 0x7fffu + ((u >> 16) & 1u);
    return (ushort)(u >> 16);
}
// split fp32 -> (hi, lo) bf16 pair; hi+lo captures f to ~2^-18 rel.
__device__ __forceinline__ void splitbf(float f, ushort& h, ushort& l) {
    h = f2bf(f);
    l = f2bf(f - bf2f(h));
}
// squash: s^2*s/((1+s^2)*sqrt(s^2)) == s*|s|/(1+s^2)
__device__ __forceinline__ float squashf(float s) {
    return s * fabsf(s) / (1.0f + s * s);
}

// ---------------------------------------------------------------------------
// Transpose+split: xTh/xTl[i][b][r] (bf16) from x[b][r][i] (fp32).
// grid (chunk=16, b=64), 256 thr; thread t: 4 consecutive r, packed 8B stores.
// ---------------------------------------------------------------------------
__global__ __launch_bounds__(256) void k_xT(const float* __restrict__ xf,
                                            ushort* __restrict__ xTh,
                                            ushort* __restrict__ xTl)
{
    const int chunk = blockIdx.x, b = blockIdx.y, t = threadIdx.x;
    const int r0 = chunk * 1024 + t * 4;
    const float* base = xf + ((size_t)b * NR_ + r0) * IC_;
    float v[4][16];
#pragma unroll
    for (int q = 0; q < 4; ++q)
#pragma unroll
        for (int s = 0; s < 4; ++s)
            *(float4*)&v[q][s * 4] = *(const float4*)(base + q * IC_ + s * 4);
#pragma unroll
    for (int i = 0; i < 16; ++i) {
        ushort h[4], l[4];
#pragma unroll
        for (int q = 0; q < 4; ++q) splitbf(v[q][i], h[q], l[q]);
        size_t idx = ((size_t)(i * B_ + b)) * NR_ + r0;
        *(uint2v*)&xTh[idx] = (uint2v){(uint)h[0] | ((uint)h[1] << 16),
                                       (uint)h[2] | ((uint)h[3] << 16)};
        *(uint2v*)&xTl[idx] = (uint2v){(uint)l[0] | ((uint)l[1] << 16),
                                       (uint)l[2] | ((uint)l[3] << 16)};
    }
}

// ---------------------------------------------------------------------------
// u_hat partials: up[kc][b][i*160+co] = sum_{r in chunk} W[i][co][r]*x[b][r][i]
// Split-bf16: xh*wh + xl*wh + xh*wl (3 MFMAs, ~fp32-exact). No atomics.
// grid (i=16, kc=32), 512 thr (8 waves), 64(b) x 160(co) x 64(k) tiles.
// ---------------------------------------------------------------------------
__global__ __launch_bounds__(512) void k_uhat(const float* __restrict__ wf,
                                              const ushort* __restrict__ xTh,
                                              const ushort* __restrict__ xTl,
                                              float* __restrict__ up)
{
    const int i    = blockIdx.x;
    const int kc   = blockIdx.y;
    const int tid  = threadIdx.x;
    const int lane = tid & 63;
    const int w    = tid >> 6;
    const int quad = lane >> 4;
    const int m16  = lane & 15;
    const int bt   = w & 3;    // b-tile (16 b's)
    const int cg   = w >> 2;   // co-group (5 co-tiles each)

    // row stride 72 elems (144 B, mult of 16): b128 frags aligned
    __shared__ ushort Xh[64 * 72], Xl[64 * 72];
    __shared__ ushort Wh[160 * 72], Wl[160 * 72];

    floatx4 acc[5];
#pragma unroll
    for (int t = 0; t < 5; ++t) acc[t] = (floatx4){0.f, 0.f, 0.f, 0.f};

    const int r0 = kc * (NR_ / KC_);

    for (int st = 0; st < (NR_ / KC_) / KT_; ++st) {   // 8 steps
        const int rb = r0 + st * KT_;
        __syncthreads();
        // ---- stage X tiles (64 b x 64 k, hi+lo): one 16B chunk each ----
        {
            int bb = tid >> 3, seg = tid & 7;
            size_t src = (size_t)(i * B_ + bb) * NR_ + rb + seg * 8;
            *(uint4v*)&Xh[bb * 72 + seg * 8] = *(const uint4v*)&xTh[src];
            *(uint4v*)&Xl[bb * 72 + seg * 8] = *(const uint4v*)&xTl[src];
        }
        // ---- stage W tiles (160 co x 64 k, fp32 -> hi+lo) ----
        for (int j = tid; j < 1280; j += 512) {
            int row = j >> 3, seg = j & 7;
            const float* wp = wf + (size_t)(i * NCO + row) * NR_ + rb + seg * 8;
            float4 f0 = *(const float4*)wp;
            float4 f1 = *(const float4*)(wp + 4);
            float v[8] = {f0.x, f0.y, f0.z, f0.w, f1.x, f1.y, f1.z, f1.w};
            ushort hh[8], ll[8];
#pragma unroll
            for (int q = 0; q < 8; ++q) splitbf(v[q], hh[q], ll[q]);
            uint4v ph, pl;
#pragma unroll
            for (int q = 0; q < 4; ++q) {
                ph[q] = (uint)hh[2 * q] | ((uint)hh[2 * q + 1] << 16);
                pl[q] = (uint)ll[2 * q] | ((uint)ll[2 * q + 1] << 16);
            }
            *(uint4v*)&Wh[row * 72 + seg * 8] = ph;
            *(uint4v*)&Wl[row * 72 + seg * 8] = pl;
        }
        __syncthreads();
        // ---- MFMA over two 32-k halves ----
#pragma unroll
        for (int kk = 0; kk < 2; ++kk) {
            bf16x8 afh = *(const bf16x8*)&Xh[(bt * 16 + m16) * 72 + kk * 32 + quad * 8];
            bf16x8 afl = *(const bf16x8*)&Xl[(bt * 16 + m16) * 72 + kk * 32 + quad * 8];
#pragma unroll
            for (int t = 0; t < 5; ++t) {
                int corow = (cg * 5 + t) * 16 + m16;
                bf16x8 bh = *(const bf16x8*)&Wh[corow * 72 + kk * 32 + quad * 8];
                bf16x8 bl = *(const bf16x8*)&Wl[corow * 72 + kk * 32 + quad * 8];
                acc[t] = __builtin_amdgcn_mfma_f32_16x16x32_bf16(afh, bh, acc[t], 0, 0, 0);
                acc[t] = __builtin_amdgcn_mfma_f32_16x16x32_bf16(afl, bh, acc[t], 0, 0, 0);
                acc[t] = __builtin_amdgcn_mfma_f32_16x16x32_bf16(afh, bl, acc[t], 0, 0, 0);
            }
        }
    }
    // epilogue: plain coalesced stores. C/D col=lane&15 (co), row=quad*4+reg (b)
#pragma unroll
    for (int t = 0; t < 5; ++t) {
        int co = (cg * 5 + t) * 16 + m16;
#pragma unroll
        for (int r = 0; r < 4; ++r) {
            int b = bt * 16 + quad * 4 + r;
            up[((size_t)kc * B_ + b) * ICO + i * NCO + co] = acc[t][r];
        }
    }
}

// ---------------------------------------------------------------------------
// Reduce partials over kc: uh[g] = sum_kc up[kc*163840 + g], g = b*2560+e.
// ---------------------------------------------------------------------------
__global__ __launch_bounds__(256) void k_reduce(const float* __restrict__ up,
                                                float* __restrict__ uh)
{
    const int g = blockIdx.x * 256 + threadIdx.x;   // < 163840
    float s = 0.f;
#pragma unroll
    for (int kc = 0; kc < KC_; ++kc) s += up[(size_t)kc * (B_ * ICO) + g];
    uh[g] = s;
}

// ---------------------------------------------------------------------------
// Routing iter 1 (uniform c): v1 -> a1p[b][i*10+c]  (per-b partial, no atomic)
// ---------------------------------------------------------------------------
__global__ __launch_bounds__(256) void k_r1(const float* __restrict__ uh,
                                            float* __restrict__ a1p)
{
    const int b = blockIdx.x, tid = threadIdx.x;
    __shared__ float uhb[ICO];
    __shared__ float vL[NCO];
    for (int e = tid; e < ICO; e += 256) uhb[e] = uh[b * ICO + e];
    __syncthreads();
    if (tid < NCO) {
        float s = 0.f;
#pragma unroll
        for (int i = 0; i < IC_; ++i) s += uhb[i * NCO + tid];
        vL[tid] = squashf(s * (1.0f / 16.0f));
    }
    __syncthreads();
    if (tid < NCO) {
        int i = tid / NC_, c = tid - i * NC_;
        float sum = 0.f;
#pragma unroll
        for (int o = 0; o < OC_; ++o)
            sum += uhb[i * NCO + c * OC_ + o] * vL[c * OC_ + o];
        a1p[b * NCO + tid] = sum * (1.0f / 64.0f);
    }
}

// ---------------------------------------------------------------------------
// Routing iter 2: c = softmax_i(a1); v2 -> a2p[b][i*10+c]
// ---------------------------------------------------------------------------
__global__ __launch_bounds__(256) void k_r2(const float* __restrict__ uh,
                                            const float* __restrict__ a1p,
                                            float* __restrict__ a2p)
{
    const int b = blockIdx.x, tid = threadIdx.x;
    __shared__ float uhb[ICO];
    __shared__ float aL[NCO];   // [i*10+c]
    __shared__ float vL[NCO];
    for (int e = tid; e < ICO; e += 256) uhb[e] = uh[b * ICO + e];
    if (tid < NCO) {
        float s = 0.f;
#pragma unroll
        for (int b2 = 0; b2 < B_; ++b2) s += a1p[b2 * NCO + tid];
        aL[tid] = s;
    }
    __syncthreads();
    if (tid < NCO) {
        int c = tid >> 4;   // tid = c*16+o
        float m = -1e30f;
        for (int i = 0; i < IC_; ++i) m = fmaxf(m, aL[i * NC_ + c]);
        float Z = 0.f;
        for (int i = 0; i < IC_; ++i) Z += expf(aL[i * NC_ + c] - m);
        float s = 0.f;
        for (int i = 0; i < IC_; ++i)
            s += (expf(aL[i * NC_ + c] - m) / Z) * uhb[i * NCO + tid];
        vL[tid] = squashf(s);
    }
    __syncthreads();
    if (tid < NCO) {
        int i = tid / NC_, c = tid - i * NC_;
        float sum = 0.f;
#pragma unroll
        for (int o = 0; o < OC_; ++o)
            sum += uhb[i * NCO + c * OC_ + o] * vL[c * OC_ + o];
        a2p[b * NCO + tid] = sum * (1.0f / 64.0f);
    }
}

// ---------------------------------------------------------------------------
// Routing iter 3 + FC head. out (fp32): [0:64) pred, [64:10304) v3[b][c][o].
// ---------------------------------------------------------------------------
__global__ __launch_bounds__(256) void k_r3(const float* __restrict__ uh,
                                            const float* __restrict__ a1p,
                                            const float* __restrict__ a2p,
                                            const float* __restrict__ fcw,
                                            const float* __restrict__ fcb,
                                            float* __restrict__ out)
{
    const int b = blockIdx.x, tid = threadIdx.x;
    __shared__ float uhb[ICO];
    __shared__ float bL[NCO];
    __shared__ float pL[NCO];
    for (int e = tid; e < ICO; e += 256) uhb[e] = uh[b * ICO + e];
    if (tid < NCO) {
        float s = 0.f;
#pragma unroll
        for (int b2 = 0; b2 < B_; ++b2)
            s += a1p[b2 * NCO + tid] + a2p[b2 * NCO + tid];
        bL[tid] = s;
    }
    __syncthreads();
    if (tid < NCO) {
        int c = tid >> 4;
        float m = -1e30f;
        for (int i = 0; i < IC_; ++i) m = fmaxf(m, bL[i * NC_ + c]);
        float Z = 0.f;
        for (int i = 0; i < IC_; ++i) Z += expf(bL[i * NC_ + c] - m);
        float s = 0.f;
        for (int i = 0; i < IC_; ++i)
            s += (expf(bL[i * NC_ + c] - m) / Z) * uhb[i * NCO + tid];
        float v = squashf(s);
        out[64 + b * NCO + tid] = v;
        pL[tid] = v * fcw[tid];
    }
    __syncthreads();
    if (tid == 0) {
        float accv = fcb[0];
        for (int j = 0; j < NCO; ++j) accv += pL[j];
        out[b] = 1.0f / (1.0f + expf(-accv));
    }
}

extern "C" void kernel_launch(void* const* d_in, const int* in_sizes, int n_in,
                              void* d_out, int out_size, void* d_ws, size_t ws_size,
                              hipStream_t stream)
{
    const float* x   = (const float*)d_in[0];
    const float* W   = (const float*)d_in[1];
    const float* fcw = (const float*)d_in[2];
    const float* fcb = (const float*)d_in[3];
    float* out = (float*)d_out;

    // ws layout (needs ~89 MB; observed ws_size ~640 MB):
    char* wsb = (char*)d_ws;
    float*  uh  = (float*)wsb;                              // 655,360 B
    float*  a1p = (float*)(wsb + 655360);                   // 40,960 B
    float*  a2p = (float*)(wsb + 696320);                   // 40,960 B
    ushort* xTh = (ushort*)(wsb + (1u << 20));              // 33.5 MB
    ushort* xTl = (ushort*)(wsb + (1u << 20) + 33554432u);  // 33.5 MB
    float*  up  = (float*)(wsb + (1u << 20) + 67108864u);   // 21 MB

    k_xT<<<dim3(16, B_), 256, 0, stream>>>(x, xTh, xTl);
    k_uhat<<<dim3(IC_, KC_), 512, 0, stream>>>(W, xTh, xTl, up);
    k_reduce<<<(B_ * ICO) / 256, 256, 0, stream>>>(up, uh);
    k_r1<<<B_, 256, 0, stream>>>(uh, a1p);
    k_r2<<<B_, 256, 0, stream>>>(uh, a1p, a2p);
    k_r3<<<B_, 256, 0, stream>>>(uh, a1p, a2p, fcw, fcb, out);
}